// Round 6
// baseline (316.236 us; speedup 1.0000x reference)
//
#include <hip/hip_runtime.h>
#include <hip/hip_bf16.h>

#define NEG_SLOPE 0.2f

typedef __attribute__((ext_vector_type(8))) short short8;   // 8 bf16 (4 VGPRs)
typedef __attribute__((ext_vector_type(4))) float f32x4;    // MFMA accumulator

__device__ __forceinline__ float bflo(unsigned u) { return __uint_as_float(u << 16); }
__device__ __forceinline__ float bfhi(unsigned u) { return __uint_as_float(u & 0xffff0000u); }
__device__ __forceinline__ unsigned pk2bf(float a, float b) {
    __hip_bfloat162 t; t.x = __float2bfloat16(a); t.y = __float2bfloat16(b);
    return *reinterpret_cast<unsigned*>(&t);
}

#define KP  136   // padded k-stride for gemm1 tiles (128+8)
#define KP2 264   // padded k-stride for gemm2 tiles (256+8)

// ============ init: edge hist + rank (blocks [0,Eb)) + weight prep (rest) ============
__global__ void k_init(const int* __restrict__ ei, int E, int* __restrict__ deg,
    int* __restrict__ rank, const float* __restrict__ W1, const float* __restrict__ W2,
    __hip_bfloat16* __restrict__ W1t, __hip_bfloat16* __restrict__ W2t, int Eb)
{
    int b = blockIdx.x;
    if (b < Eb) {
        int i = b * 256 + threadIdx.x;
        if (i < E) {
            int dst = ei[E + i];
            rank[i] = atomicAdd(&deg[dst], 1);
        }
    } else {
        int i = (b - Eb) * 256 + threadIdx.x;
        if (i < 256 * KP) {
            int n = i / KP, k = i % KP;
            W1t[i] = __float2bfloat16(k < 128 ? W1[k * 256 + n] : 0.f);
        } else {
            int j = i - 256 * KP;
            if (j < 64 * KP2) {
                int n = j / KP2, k = j % KP2;
                W2t[j] = __float2bfloat16(k < 256 ? W2[k * 64 + n] : 0.f);
            }
        }
    }
}

// ============ scan1: per-256-block inclusive scan of (deg+1) -> excl + bsum ============
__global__ __launch_bounds__(256) void k_scan1(const int* __restrict__ deg, int N,
    int* __restrict__ excl, int* __restrict__ bsum)
{
    __shared__ int s[256];
    int t = threadIdx.x, i = blockIdx.x * 256 + t;
    int v = (i < N) ? deg[i] + 1 : 0;
    s[t] = v; __syncthreads();
#pragma unroll
    for (int o = 1; o < 256; o <<= 1) {
        int x = (t >= o) ? s[t - o] : 0;
        __syncthreads();
        s[t] += x;
        __syncthreads();
    }
    if (i < N) excl[i] = s[t] - v;
    if (t == 255) bsum[blockIdx.x] = s[255];
}

// ============ scatter: atomic-free (rank precomputed); self-loop at slot 0 ============
__global__ void k_scatter(const int* __restrict__ ei, const int* __restrict__ rank,
    int E, int N, const int* __restrict__ rowptr, int* __restrict__ csr_src)
{
    int i = blockIdx.x * blockDim.x + threadIdx.x;
    if (i < E) {
        int src = ei[i], dst = ei[E + i];
        csr_src[rowptr[dst] + 1 + rank[i]] = src;
    } else if (i < E + N) {
        int n = i - E;
        csr_src[rowptr[n]] = n;
    }
}

// ============ Layer 1 GEMM via MFMA + fused att dots + piggybacked scan23 ============
// h1 output is HEAD-MAJOR: h1h[h][N][64] (four contiguous 6.4MB tables) so the
// aggregate kernel can keep one head's table per XCD-L2. Att dots head-major too.
__global__ __launch_bounds__(256) void k_gemm1_mfma(
    const float* __restrict__ x, const __hip_bfloat16* __restrict__ W1t,
    const float* __restrict__ as1, const float* __restrict__ ad1,
    __hip_bfloat16* __restrict__ h1h, float* __restrict__ a_s1h, float* __restrict__ a_d1h,
    int N, int M, const int* __restrict__ excl, const int* __restrict__ bsum,
    int* __restrict__ rowptr, int NB, int G1x)
{
    __shared__ short sA[64 * KP];
    __shared__ short sB[128 * KP];

    if (blockIdx.x >= G1x) {
        int sb = (blockIdx.x - G1x) * 2 + blockIdx.y;
        if (sb >= NB) return;
        int* s = (int*)sA;
        int t = threadIdx.x;
        s[t] = (t < NB) ? bsum[t] : 0;
        __syncthreads();
#pragma unroll
        for (int o = 1; o < 256; o <<= 1) {
            int y = (t >= o) ? s[t - o] : 0;
            __syncthreads();
            s[t] += y;
            __syncthreads();
        }
        int off = (sb == 0) ? 0 : s[sb - 1];
        int i = sb * 256 + t;
        if (i < N) rowptr[i] = excl[i] + off;
        if (i == 0) rowptr[N] = M;
        return;
    }

    const int n0 = blockIdx.x * 64;
    const int c0 = blockIdx.y * 128;
    const int t = threadIdx.x, wv = t >> 6, lane = t & 63;
    const int l15 = lane & 15, q = lane >> 4;

    {
        const float4* x4 = (const float4*)x;
        for (int i = t; i < 2048; i += 256) {
            int row = i >> 5, kq = i & 31;
            float4 v = make_float4(0.f, 0.f, 0.f, 0.f);
            if (n0 + row < N) v = x4[(size_t)(n0 + row) * 32 + kq];
            uint2 p; p.x = pk2bf(v.x, v.y); p.y = pk2bf(v.z, v.w);
            *(uint2*)(sA + row * KP + kq * 4) = p;
        }
    }
    {
        const uint4* src = (const uint4*)((const short*)W1t + (size_t)c0 * KP);
        uint4* dst = (uint4*)sB;
        for (int i = t; i < (128 * KP * 2) / 16; i += 256) dst[i] = src[i];
    }
    __syncthreads();

    short8 af[4];
#pragma unroll
    for (int kc = 0; kc < 4; ++kc)
        af[kc] = *(const short8*)(sA + (wv * 16 + l15) * KP + kc * 32 + q * 8);

    f32x4 acc[8];
#pragma unroll
    for (int nt = 0; nt < 8; ++nt) {
        f32x4 a = {0.f, 0.f, 0.f, 0.f};
#pragma unroll
        for (int kc = 0; kc < 4; ++kc) {
            short8 bf = *(const short8*)(sB + (nt * 16 + l15) * KP + kc * 32 + q * 8);
            a = __builtin_amdgcn_mfma_f32_16x16x32_bf16(af[kc], bf, a, 0, 0, 0);
        }
        acc[nt] = a;
    }

    // head-major store: col = c0 + nt*16 + l15 -> table col>>6, inner col&63
#pragma unroll
    for (int nt = 0; nt < 8; ++nt) {
        int col = c0 + nt * 16 + l15;
        __hip_bfloat16* tp = h1h + ((size_t)(col >> 6) * N) * 64 + (col & 63);
#pragma unroll
        for (int r = 0; r < 4; ++r) {
            int row = n0 + wv * 16 + q * 4 + r;
            if (row < N)
                tp[(size_t)row * 64] = __float2bfloat16(acc[nt][r]);
        }
    }

    float asv[8], adv[8];
#pragma unroll
    for (int nt = 0; nt < 8; ++nt) {
        asv[nt] = as1[c0 + nt * 16 + l15];
        adv[nt] = ad1[c0 + nt * 16 + l15];
    }
    const int hb = blockIdx.y * 2;
#pragma unroll
    for (int r = 0; r < 4; ++r) {
        float slo = 0.f, shi = 0.f, dlo = 0.f, dhi = 0.f;
#pragma unroll
        for (int nt = 0; nt < 4; ++nt) { slo += acc[nt][r] * asv[nt]; dlo += acc[nt][r] * adv[nt]; }
#pragma unroll
        for (int nt = 4; nt < 8; ++nt) { shi += acc[nt][r] * asv[nt]; dhi += acc[nt][r] * adv[nt]; }
#pragma unroll
        for (int o = 1; o < 16; o <<= 1) {
            slo += __shfl_xor(slo, o); shi += __shfl_xor(shi, o);
            dlo += __shfl_xor(dlo, o); dhi += __shfl_xor(dhi, o);
        }
        int row = n0 + wv * 16 + q * 4 + r;
        if (l15 == 0 && row < N) {
            a_s1h[(size_t)hb * N + row]       = slo;
            a_s1h[(size_t)(hb + 1) * N + row] = shi;
            a_d1h[(size_t)hb * N + row]       = dlo;
            a_d1h[(size_t)(hb + 1) * N + row] = dhi;
        }
    }
}

// ============ Layer 1 head-split softmax+aggregate+bias+ELU ============
// head = blockIdx.x % 4 -> with round-robin block->XCD dispatch, XCDs {h, h+4}
// touch ONLY head h's contiguous 6.4MB table (vs 25.6MB) -> L2 hit rate up,
// L3->L2 fetch down ~2x. One dst per wave; 8 edge-slots (l>>3) x 8 chunks (l&7,
// uint4): one wave-wide load = 1KB = 8 edges. exp count unchanged (1 head/block).
__global__ __launch_bounds__(256) void k_agg1h(const int* __restrict__ rowptr,
    const int* __restrict__ csr_src, const float* __restrict__ a_s1h,
    const float* __restrict__ a_d1h, const __hip_bfloat16* __restrict__ h1h,
    const float* __restrict__ b1, __hip_bfloat16* __restrict__ h2b, int N)
{
    const int tt = threadIdx.x, wv = tt >> 6, l = tt & 63;
    const int h = blockIdx.x & 3;
    const int dgrp = blockIdx.x >> 2;
    const int slot = l >> 3, c = l & 7;
    const char* tab = (const char*)(h1h + (size_t)h * N * 64);
    const float* ash = a_s1h + (size_t)h * N;
    __shared__ int   s_off[4][8];
    __shared__ float s_ex[4][8];
#pragma unroll 1
    for (int i = 0; i < 4; ++i) {
        int dst = dgrp * 16 + wv * 4 + i;
        if (dst >= N) return;
        int st = rowptr[dst], en = rowptr[dst + 1];
        float adh = a_d1h[(size_t)h * N + dst];
        float a0 = 0.f, a1 = 0.f, a2 = 0.f, a3 = 0.f;
        float a4 = 0.f, a5 = 0.f, a6 = 0.f, a7 = 0.f;
        float dn = 0.f;
#pragma unroll 1
        for (int base = st; base < en; base += 8) {
            if (l < 8) {
                int m = base + l;
                bool k = m < en;
                int src = csr_src[k ? m : st];
                float e = ash[src] + adh;
                e = e > 0.f ? e : NEG_SLOPE * e;
                float ex = k ? __expf(e) : 0.f;
                s_off[wv][l] = src << 7;          // byte offset src*128
                s_ex[wv][l] = ex;
                dn += ex;
            }
            uint4 v = *(const uint4*)(tab + (size_t)(unsigned)s_off[wv][slot] + c * 16);
            float ex = s_ex[wv][slot];
            a0 += ex * bflo(v.x); a1 += ex * bfhi(v.x);
            a2 += ex * bflo(v.y); a3 += ex * bfhi(v.y);
            a4 += ex * bflo(v.z); a5 += ex * bfhi(v.z);
            a6 += ex * bflo(v.w); a7 += ex * bfhi(v.w);
        }
        // reduce col-partials over slot axis (lane bits 3..5)
#pragma unroll
        for (int o = 8; o < 64; o <<= 1) {
            a0 += __shfl_xor(a0, o); a1 += __shfl_xor(a1, o);
            a2 += __shfl_xor(a2, o); a3 += __shfl_xor(a3, o);
            a4 += __shfl_xor(a4, o); a5 += __shfl_xor(a5, o);
            a6 += __shfl_xor(a6, o); a7 += __shfl_xor(a7, o);
        }
        // den reduce within lanes 0..7 (dn only valid there)
        dn += __shfl_xor(dn, 1); dn += __shfl_xor(dn, 2); dn += __shfl_xor(dn, 4);
        if (l < 8) {
            float inv = 1.0f / dn;
            float4 bb0 = ((const float4*)b1)[h * 16 + l * 2];
            float4 bb1 = ((const float4*)b1)[h * 16 + l * 2 + 1];
            float v0 = a0 * inv + bb0.x; v0 = v0 > 0.f ? v0 : (__expf(v0) - 1.f);
            float v1 = a1 * inv + bb0.y; v1 = v1 > 0.f ? v1 : (__expf(v1) - 1.f);
            float v2 = a2 * inv + bb0.z; v2 = v2 > 0.f ? v2 : (__expf(v2) - 1.f);
            float v3 = a3 * inv + bb0.w; v3 = v3 > 0.f ? v3 : (__expf(v3) - 1.f);
            float v4 = a4 * inv + bb1.x; v4 = v4 > 0.f ? v4 : (__expf(v4) - 1.f);
            float v5 = a5 * inv + bb1.y; v5 = v5 > 0.f ? v5 : (__expf(v5) - 1.f);
            float v6 = a6 * inv + bb1.z; v6 = v6 > 0.f ? v6 : (__expf(v6) - 1.f);
            float v7 = a7 * inv + bb1.w; v7 = v7 > 0.f ? v7 : (__expf(v7) - 1.f);
            uint4 pkt;
            pkt.x = pk2bf(v0, v1); pkt.y = pk2bf(v2, v3);
            pkt.z = pk2bf(v4, v5); pkt.w = pk2bf(v6, v7);
            *(uint4*)((char*)h2b + (size_t)dst * 512 + h * 128 + l * 16) = pkt;
        }
    }
}

// ============ Layer 2 GEMM via MFMA + fused att dots (direct stores) ============
__global__ __launch_bounds__(256) void k_gemm2_mfma(
    const __hip_bfloat16* __restrict__ h2b, const __hip_bfloat16* __restrict__ W2t,
    const float* __restrict__ as2, const float* __restrict__ ad2,
    __hip_bfloat16* __restrict__ h3b, float* __restrict__ a_s2, float* __restrict__ a_d2,
    int N)
{
    const int n0 = blockIdx.x * 32;
    const int t = threadIdx.x, wv = t >> 6, lane = t & 63;
    const int l15 = lane & 15, q = lane >> 4;
    const int rs = wv & 1, ch = wv >> 1;

    __shared__ short sA[32 * KP2];
    __shared__ short sB[64 * KP2];

    {
        const uint4* src = (const uint4*)W2t;
        uint4* dst = (uint4*)sB;
        for (int i = t; i < (64 * KP2 * 2) / 16; i += 256) dst[i] = src[i];
    }
    {
        for (int i = t; i < 1024; i += 256) {
            int row = i >> 5, kq = i & 31;
            uint4 v = make_uint4(0, 0, 0, 0);
            if (n0 + row < N) v = ((const uint4*)(h2b + (size_t)(n0 + row) * 256))[kq];
            *(uint4*)(sA + row * KP2 + kq * 8) = v;
        }
    }
    __syncthreads();

    short8 af[8];
#pragma unroll
    for (int kc = 0; kc < 8; ++kc)
        af[kc] = *(const short8*)(sA + (rs * 16 + l15) * KP2 + kc * 32 + q * 8);

    f32x4 acc[2];
#pragma unroll
    for (int nt = 0; nt < 2; ++nt) {
        f32x4 a = {0.f, 0.f, 0.f, 0.f};
#pragma unroll
        for (int kc = 0; kc < 8; ++kc) {
            short8 bf = *(const short8*)(sB + (ch * 32 + nt * 16 + l15) * KP2 + kc * 32 + q * 8);
            a = __builtin_amdgcn_mfma_f32_16x16x32_bf16(af[kc], bf, a, 0, 0, 0);
        }
        acc[nt] = a;
    }

    float asv[2], adv[2];
#pragma unroll
    for (int nt = 0; nt < 2; ++nt) {
        int col = ch * 32 + nt * 16 + l15;
        asv[nt] = as2[col]; adv[nt] = ad2[col];
    }
#pragma unroll
    for (int r = 0; r < 4; ++r) {
        int row = n0 + rs * 16 + q * 4 + r;
        if (row < N) {
#pragma unroll
            for (int nt = 0; nt < 2; ++nt)
                h3b[(size_t)row * 64 + ch * 32 + nt * 16 + l15] = __float2bfloat16(acc[nt][r]);
        }
        float s = acc[0][r] * asv[0] + acc[1][r] * asv[1];
        float d = acc[0][r] * adv[0] + acc[1][r] * adv[1];
#pragma unroll
        for (int o = 1; o < 16; o <<= 1) { s += __shfl_xor(s, o); d += __shfl_xor(d, o); }
        if (l15 == 0 && row < N) {
            atomicAdd(&a_s2[row], s);
            atomicAdd(&a_d2[row], d);
        }
    }
}

// ============ Layer 2 fused softmax+aggregate + b2 -> out ============
// 8 dsts/block (4 waves x two 32-lane halves), no barriers, 16-deep ILP.
__global__ __launch_bounds__(256) void k_agg2_fused(const int* __restrict__ rowptr,
    const int* __restrict__ csr_src, const float* __restrict__ a_s2,
    const float* __restrict__ a_d2, const __hip_bfloat16* __restrict__ h3b,
    const float* __restrict__ b2, float* __restrict__ out, int N)
{
    const int tt = threadIdx.x, wv = tt >> 6, t = tt & 63;
    const int half = t >> 5, l = t & 31;
    const int dst = blockIdx.x * 8 + wv * 2 + half;
    const bool valid = dst < N;
    __shared__ int   s_off[4][2][32];
    __shared__ float s_ex[4][2][32];
    int start = 0, end = 0;
    float adv = 0.f;
    if (valid) { start = rowptr[dst]; end = rowptr[dst + 1]; adv = a_d2[dst]; }
    int trips = (end - start + 31) >> 5;
#pragma unroll
    for (int o = 32; o > 0; o >>= 1) { int u = __shfl_xor(trips, o); trips = u > trips ? u : trips; }
    const char* hbase = (const char*)h3b;
    float den = 0.f, acc0 = 0.f, acc1 = 0.f;

    for (int it = 0; it < trips; ++it) {
        int base = start + it * 32;
        int nloc = end - base; if (nloc > 32) nloc = 32; if (nloc < 0) nloc = 0;
        if (l < nloc) {
            int src = csr_src[base + l];
            s_off[wv][half][l] = src << 7;               // byte offset src*128
            float e = a_s2[src] + adv;
            e = e > 0.f ? e : NEG_SLOPE * e;
            float ex = __expf(e);
            s_ex[wv][half][l] = ex;
            den += ex;
        }
        int j = 0;
        for (; j + 15 < nloc; j += 16) {
            unsigned v[16];
#pragma unroll
            for (int q = 0; q < 16; ++q)
                v[q] = *(const unsigned*)(hbase + (size_t)(unsigned)s_off[wv][half][j + q] + l * 4);
#pragma unroll
            for (int q = 0; q < 16; ++q) {
                float e = s_ex[wv][half][j + q];
                acc0 += e * bflo(v[q]); acc1 += e * bfhi(v[q]);
            }
        }
        for (; j + 7 < nloc; j += 8) {
            unsigned v[8];
#pragma unroll
            for (int q = 0; q < 8; ++q)
                v[q] = *(const unsigned*)(hbase + (size_t)(unsigned)s_off[wv][half][j + q] + l * 4);
#pragma unroll
            for (int q = 0; q < 8; ++q) {
                float e = s_ex[wv][half][j + q];
                acc0 += e * bflo(v[q]); acc1 += e * bfhi(v[q]);
            }
        }
        for (; j < nloc; ++j) {
            unsigned v = *(const unsigned*)(hbase + (size_t)(unsigned)s_off[wv][half][j] + l * 4);
            float e = s_ex[wv][half][j];
            acc0 += e * bflo(v); acc1 += e * bfhi(v);
        }
    }
#pragma unroll
    for (int o = 16; o > 0; o >>= 1) den += __shfl_xor(den, o);
    if (valid) {
        float inv = 1.0f / den;
        float2 bb = ((const float2*)b2)[l];
        float2 ov; ov.x = acc0 * inv + bb.x; ov.y = acc1 * inv + bb.y;
        ((float2*)(out + (size_t)dst * 64))[l] = ov;
    }
}

extern "C" void kernel_launch(void* const* d_in, const int* in_sizes, int n_in,
                              void* d_out, int out_size, void* d_ws, size_t ws_size,
                              hipStream_t stream)
{
    const float* x   = (const float*)d_in[0];
    const int*   ei  = (const int*)d_in[1];
    const float* W1  = (const float*)d_in[2];
    const float* as1 = (const float*)d_in[3];
    const float* ad1 = (const float*)d_in[4];
    const float* b1  = (const float*)d_in[5];
    const float* W2  = (const float*)d_in[6];
    const float* as2 = (const float*)d_in[7];
    const float* ad2 = (const float*)d_in[8];
    const float* b2  = (const float*)d_in[9];
    float* out = (float*)d_out;

    const int N = in_sizes[0] / 128;      // 50000
    const int E = in_sizes[1] / 2;        // 800000
    const int M = E + N;                  // edges + self loops
    const int NB = (N + 255) / 256;       // scan blocks (196 <= 256)
    const int Eb = (E + 255) / 256;

    // ---- workspace layout (256B-aligned) ----
    char* w = (char*)d_ws;
    size_t o = 0;
    auto alloc = [&](size_t bytes) { size_t r = o; o = (o + bytes + 255) & ~(size_t)255; return r; };
    __hip_bfloat16* h1h   = (__hip_bfloat16*)(w + alloc((size_t)N * 256 * 2)); // 25.6 MB (4 head tables)
    float* a_s1h          = (float*)(w + alloc((size_t)N * 4 * 4));
    float* a_d1h          = (float*)(w + alloc((size_t)N * 4 * 4));
    __hip_bfloat16* h2b   = (__hip_bfloat16*)(w + alloc((size_t)N * 256 * 2)); // 25.6 MB
    __hip_bfloat16* h3b   = (__hip_bfloat16*)(w + alloc((size_t)N * 64 * 2));  // 6.4 MB
    // zero-block: a_s2 | a_d2 | deg — one memset covers the span
    size_t z0 = o;
    float* a_s2           = (float*)(w + alloc((size_t)N * 4));
    float* a_d2           = (float*)(w + alloc((size_t)N * 4));
    int* deg              = (int*)(w + alloc((size_t)N * 4));
    size_t z1 = o;
    int* rank             = (int*)(w + alloc((size_t)E * 4));                  // 3.2 MB
    int* rowptr           = (int*)(w + alloc((size_t)(N + 1) * 4));
    int* excl             = (int*)(w + alloc((size_t)N * 4));
    int* bsum             = (int*)(w + alloc((size_t)NB * 4));
    int* csr_src          = (int*)(w + alloc((size_t)M * 4));                  // 3.4 MB
    __hip_bfloat16* W1t   = (__hip_bfloat16*)(w + alloc((size_t)256 * KP * 2));
    __hip_bfloat16* W2t   = (__hip_bfloat16*)(w + alloc((size_t)64 * KP2 * 2));

    // ---- zero + init (edge hist/rank + weight prep fused) ----
    hipMemsetAsync(w + z0, 0, z1 - z0, stream);
    const int Pb = (256 * KP + 64 * KP2 + 255) / 256;
    k_init<<<Eb + Pb, 256, 0, stream>>>(ei, E, deg, rank, W1, W2, W1t, W2t, Eb);

    // ---- scan1 (tiny), then gemm1 (+ piggybacked scan23) ----
    k_scan1<<<NB, 256, 0, stream>>>(deg, N, excl, bsum);
    const int G1x = (N + 63) / 64;
    k_gemm1_mfma<<<dim3(G1x + (NB + 1) / 2, 2), 256, 0, stream>>>(
        x, W1t, as1, ad1, h1h, a_s1h, a_d1h, N, M, excl, bsum, rowptr, NB, G1x);

    // ---- scatter (atomic-free) ----
    k_scatter<<<(M + 255) / 256, 256, 0, stream>>>(ei, rank, E, N, rowptr, csr_src);

    // ---- layer 1 aggregate: head-split (head = blockIdx%4 -> XCD pair) ----
    const int DG1 = (N + 15) / 16;
    k_agg1h<<<4 * DG1, 256, 0, stream>>>(rowptr, csr_src, a_s1h, a_d1h, h1h, b1, h2b, N);

    // ---- layer 2 ----
    k_gemm2_mfma<<<(N + 31) / 32, 256, 0, stream>>>(h2b, W2t, as2, ad2, h3b, a_s2, a_d2, N);
    k_agg2_fused<<<(N + 7) / 8, 256, 0, stream>>>(rowptr, csr_src, a_s2, a_d2, h3b, b2, out, N);
}

// Round 7
// 257.473 us; speedup vs baseline: 1.2282x; 1.2282x over previous
//
#include <hip/hip_runtime.h>
#include <hip/hip_bf16.h>

#define NEG_SLOPE 0.2f

typedef __attribute__((ext_vector_type(8))) short short8;   // 8 bf16 (4 VGPRs)
typedef __attribute__((ext_vector_type(4))) float f32x4;    // MFMA accumulator

__device__ __forceinline__ float bflo(unsigned u) { return __uint_as_float(u << 16); }
__device__ __forceinline__ float bfhi(unsigned u) { return __uint_as_float(u & 0xffff0000u); }
__device__ __forceinline__ unsigned pk2bf(float a, float b) {
    __hip_bfloat162 t; t.x = __float2bfloat16(a); t.y = __float2bfloat16(b);
    return *reinterpret_cast<unsigned*>(&t);
}

#define KP  136   // padded k-stride for gemm1 tiles (128+8)
#define KP2 264   // padded k-stride for gemm2 tiles (256+8)

// ============ init: edge hist + rank (blocks [0,Eb)) + weight prep (rest) ============
__global__ void k_init(const int* __restrict__ ei, int E, int* __restrict__ deg,
    int* __restrict__ rank, const float* __restrict__ W1, const float* __restrict__ W2,
    __hip_bfloat16* __restrict__ W1t, __hip_bfloat16* __restrict__ W2t, int Eb)
{
    int b = blockIdx.x;
    if (b < Eb) {
        int i = b * 256 + threadIdx.x;
        if (i < E) {
            int dst = ei[E + i];
            rank[i] = atomicAdd(&deg[dst], 1);
        }
    } else {
        int i = (b - Eb) * 256 + threadIdx.x;
        if (i < 256 * KP) {
            int n = i / KP, k = i % KP;
            W1t[i] = __float2bfloat16(k < 128 ? W1[k * 256 + n] : 0.f);
        } else {
            int j = i - 256 * KP;
            if (j < 64 * KP2) {
                int n = j / KP2, k = j % KP2;
                W2t[j] = __float2bfloat16(k < 256 ? W2[k * 64 + n] : 0.f);
            }
        }
    }
}

// ============ scan1: per-256-block inclusive scan of (deg+1) -> excl + bsum ============
__global__ __launch_bounds__(256) void k_scan1(const int* __restrict__ deg, int N,
    int* __restrict__ excl, int* __restrict__ bsum)
{
    __shared__ int s[256];
    int t = threadIdx.x, i = blockIdx.x * 256 + t;
    int v = (i < N) ? deg[i] + 1 : 0;
    s[t] = v; __syncthreads();
#pragma unroll
    for (int o = 1; o < 256; o <<= 1) {
        int x = (t >= o) ? s[t - o] : 0;
        __syncthreads();
        s[t] += x;
        __syncthreads();
    }
    if (i < N) excl[i] = s[t] - v;
    if (t == 255) bsum[blockIdx.x] = s[255];
}

// ============ scatter: atomic-free (rank precomputed); self-loop at slot 0 ============
__global__ void k_scatter(const int* __restrict__ ei, const int* __restrict__ rank,
    int E, int N, const int* __restrict__ rowptr, int* __restrict__ csr_src)
{
    int i = blockIdx.x * blockDim.x + threadIdx.x;
    if (i < E) {
        int src = ei[i], dst = ei[E + i];
        csr_src[rowptr[dst] + 1 + rank[i]] = src;
    } else if (i < E + N) {
        int n = i - E;
        csr_src[rowptr[n]] = n;
    }
}

// ============ Layer 1 GEMM via MFMA + fused att dots + piggybacked scan23 ============
// h1 output is HEAD-MAJOR: h1h[h][N][64] (four contiguous 6.4MB tables) so the
// aggregate kernel can keep one head's table per XCD-L2. Att dots head-major too.
__global__ __launch_bounds__(256) void k_gemm1_mfma(
    const float* __restrict__ x, const __hip_bfloat16* __restrict__ W1t,
    const float* __restrict__ as1, const float* __restrict__ ad1,
    __hip_bfloat16* __restrict__ h1h, float* __restrict__ a_s1h, float* __restrict__ a_d1h,
    int N, int M, const int* __restrict__ excl, const int* __restrict__ bsum,
    int* __restrict__ rowptr, int NB, int G1x)
{
    __shared__ short sA[64 * KP];
    __shared__ short sB[128 * KP];

    if (blockIdx.x >= G1x) {
        int sb = (blockIdx.x - G1x) * 2 + blockIdx.y;
        if (sb >= NB) return;
        int* s = (int*)sA;
        int t = threadIdx.x;
        s[t] = (t < NB) ? bsum[t] : 0;
        __syncthreads();
#pragma unroll
        for (int o = 1; o < 256; o <<= 1) {
            int y = (t >= o) ? s[t - o] : 0;
            __syncthreads();
            s[t] += y;
            __syncthreads();
        }
        int off = (sb == 0) ? 0 : s[sb - 1];
        int i = sb * 256 + t;
        if (i < N) rowptr[i] = excl[i] + off;
        if (i == 0) rowptr[N] = M;
        return;
    }

    const int n0 = blockIdx.x * 64;
    const int c0 = blockIdx.y * 128;
    const int t = threadIdx.x, wv = t >> 6, lane = t & 63;
    const int l15 = lane & 15, q = lane >> 4;

    {
        const float4* x4 = (const float4*)x;
        for (int i = t; i < 2048; i += 256) {
            int row = i >> 5, kq = i & 31;
            float4 v = make_float4(0.f, 0.f, 0.f, 0.f);
            if (n0 + row < N) v = x4[(size_t)(n0 + row) * 32 + kq];
            uint2 p; p.x = pk2bf(v.x, v.y); p.y = pk2bf(v.z, v.w);
            *(uint2*)(sA + row * KP + kq * 4) = p;
        }
    }
    {
        const uint4* src = (const uint4*)((const short*)W1t + (size_t)c0 * KP);
        uint4* dst = (uint4*)sB;
        for (int i = t; i < (128 * KP * 2) / 16; i += 256) dst[i] = src[i];
    }
    __syncthreads();

    short8 af[4];
#pragma unroll
    for (int kc = 0; kc < 4; ++kc)
        af[kc] = *(const short8*)(sA + (wv * 16 + l15) * KP + kc * 32 + q * 8);

    f32x4 acc[8];
#pragma unroll
    for (int nt = 0; nt < 8; ++nt) {
        f32x4 a = {0.f, 0.f, 0.f, 0.f};
#pragma unroll
        for (int kc = 0; kc < 4; ++kc) {
            short8 bf = *(const short8*)(sB + (nt * 16 + l15) * KP + kc * 32 + q * 8);
            a = __builtin_amdgcn_mfma_f32_16x16x32_bf16(af[kc], bf, a, 0, 0, 0);
        }
        acc[nt] = a;
    }

    // head-major store: col = c0 + nt*16 + l15 -> table col>>6, inner col&63
#pragma unroll
    for (int nt = 0; nt < 8; ++nt) {
        int col = c0 + nt * 16 + l15;
        __hip_bfloat16* tp = h1h + ((size_t)(col >> 6) * N) * 64 + (col & 63);
#pragma unroll
        for (int r = 0; r < 4; ++r) {
            int row = n0 + wv * 16 + q * 4 + r;
            if (row < N)
                tp[(size_t)row * 64] = __float2bfloat16(acc[nt][r]);
        }
    }

    float asv[8], adv[8];
#pragma unroll
    for (int nt = 0; nt < 8; ++nt) {
        asv[nt] = as1[c0 + nt * 16 + l15];
        adv[nt] = ad1[c0 + nt * 16 + l15];
    }
    const int hb = blockIdx.y * 2;
#pragma unroll
    for (int r = 0; r < 4; ++r) {
        float slo = 0.f, shi = 0.f, dlo = 0.f, dhi = 0.f;
#pragma unroll
        for (int nt = 0; nt < 4; ++nt) { slo += acc[nt][r] * asv[nt]; dlo += acc[nt][r] * adv[nt]; }
#pragma unroll
        for (int nt = 4; nt < 8; ++nt) { shi += acc[nt][r] * asv[nt]; dhi += acc[nt][r] * adv[nt]; }
#pragma unroll
        for (int o = 1; o < 16; o <<= 1) {
            slo += __shfl_xor(slo, o); shi += __shfl_xor(shi, o);
            dlo += __shfl_xor(dlo, o); dhi += __shfl_xor(dhi, o);
        }
        int row = n0 + wv * 16 + q * 4 + r;
        if (l15 == 0 && row < N) {
            a_s1h[(size_t)hb * N + row]       = slo;
            a_s1h[(size_t)(hb + 1) * N + row] = shi;
            a_d1h[(size_t)hb * N + row]       = dlo;
            a_d1h[(size_t)(hb + 1) * N + row] = dhi;
        }
    }
}

// ============ Layer 1 head-split aggregate, 8-lane group per dst ============
// head = blockIdx.x % 4 (XCD-local 6.4MB table, proven -44% FETCH in r6).
// Wave = 8 groups of 8 lanes; group g owns dst dgrp*32+wv*8+g. Lane c owns cols
// [8c,8c+8): NO cross-lane accumulator reduce (r5's trick). Per 8-edge batch:
// lane c computes edge (base+c)'s exp into LDS, then 8 uint4 loads IN FLIGHT
// (j=0..7) + 64 FMAs. 1KB per wave-wide load inst; den reduce = 3 shuffles.
__global__ __launch_bounds__(256) void k_agg1g(const int* __restrict__ rowptr,
    const int* __restrict__ csr_src, const float* __restrict__ a_s1h,
    const float* __restrict__ a_d1h, const __hip_bfloat16* __restrict__ h1h,
    const float* __restrict__ b1, __hip_bfloat16* __restrict__ h2b, int N)
{
    const int tt = threadIdx.x, wv = tt >> 6, l = tt & 63;
    const int h = blockIdx.x & 3;
    const int dgrp = blockIdx.x >> 2;
    const int g = l >> 3, c = l & 7;
    const char* tab = (const char*)(h1h + (size_t)h * N * 64);
    const float* ash = a_s1h + (size_t)h * N;
    __shared__ int   s_off[4][8][8];
    __shared__ float s_ex[4][8][8];

    const int dst = dgrp * 32 + wv * 8 + g;
    const bool valid = dst < N;
    int st = 0, en = 0;
    if (valid) { st = rowptr[dst]; en = rowptr[dst + 1]; }
    float adh = valid ? a_d1h[(size_t)h * N + dst] : 0.f;
    float a0 = 0.f, a1 = 0.f, a2 = 0.f, a3 = 0.f;
    float a4 = 0.f, a5 = 0.f, a6 = 0.f, a7 = 0.f;
    float dn = 0.f;

    for (int base = st; base < en; base += 8) {
        int m = base + c;
        bool k = m < en;
        int src = csr_src[k ? m : st];
        float e = ash[src] + adh;
        e = e > 0.f ? e : NEG_SLOPE * e;
        float ex = k ? __expf(e) : 0.f;
        s_off[wv][g][c] = src << 7;               // byte offset src*128
        s_ex[wv][g][c] = ex;
        dn += ex;
        uint4 v[8];
#pragma unroll
        for (int j = 0; j < 8; ++j)
            v[j] = *(const uint4*)(tab + (size_t)(unsigned)s_off[wv][g][j] + c * 16);
#pragma unroll
        for (int j = 0; j < 8; ++j) {
            float exj = s_ex[wv][g][j];
            a0 += exj * bflo(v[j].x); a1 += exj * bfhi(v[j].x);
            a2 += exj * bflo(v[j].y); a3 += exj * bfhi(v[j].y);
            a4 += exj * bflo(v[j].z); a5 += exj * bfhi(v[j].z);
            a6 += exj * bflo(v[j].w); a7 += exj * bfhi(v[j].w);
        }
    }
    // denominator reduce within the 8-lane group
    dn += __shfl_xor(dn, 1); dn += __shfl_xor(dn, 2); dn += __shfl_xor(dn, 4);
    if (!valid) return;
    float inv = 1.0f / dn;
    float4 bb0 = ((const float4*)b1)[h * 16 + c * 2];
    float4 bb1 = ((const float4*)b1)[h * 16 + c * 2 + 1];
    float v0 = a0 * inv + bb0.x; v0 = v0 > 0.f ? v0 : (__expf(v0) - 1.f);
    float v1 = a1 * inv + bb0.y; v1 = v1 > 0.f ? v1 : (__expf(v1) - 1.f);
    float v2 = a2 * inv + bb0.z; v2 = v2 > 0.f ? v2 : (__expf(v2) - 1.f);
    float v3 = a3 * inv + bb0.w; v3 = v3 > 0.f ? v3 : (__expf(v3) - 1.f);
    float v4 = a4 * inv + bb1.x; v4 = v4 > 0.f ? v4 : (__expf(v4) - 1.f);
    float v5 = a5 * inv + bb1.y; v5 = v5 > 0.f ? v5 : (__expf(v5) - 1.f);
    float v6 = a6 * inv + bb1.z; v6 = v6 > 0.f ? v6 : (__expf(v6) - 1.f);
    float v7 = a7 * inv + bb1.w; v7 = v7 > 0.f ? v7 : (__expf(v7) - 1.f);
    uint4 pkt;
    pkt.x = pk2bf(v0, v1); pkt.y = pk2bf(v2, v3);
    pkt.z = pk2bf(v4, v5); pkt.w = pk2bf(v6, v7);
    *(uint4*)((char*)h2b + (size_t)dst * 512 + h * 128 + c * 16) = pkt;
}

// ============ Layer 2 GEMM via MFMA + fused att dots (direct stores) ============
__global__ __launch_bounds__(256) void k_gemm2_mfma(
    const __hip_bfloat16* __restrict__ h2b, const __hip_bfloat16* __restrict__ W2t,
    const float* __restrict__ as2, const float* __restrict__ ad2,
    __hip_bfloat16* __restrict__ h3b, float* __restrict__ a_s2, float* __restrict__ a_d2,
    int N)
{
    const int n0 = blockIdx.x * 32;
    const int t = threadIdx.x, wv = t >> 6, lane = t & 63;
    const int l15 = lane & 15, q = lane >> 4;
    const int rs = wv & 1, ch = wv >> 1;

    __shared__ short sA[32 * KP2];
    __shared__ short sB[64 * KP2];

    {
        const uint4* src = (const uint4*)W2t;
        uint4* dst = (uint4*)sB;
        for (int i = t; i < (64 * KP2 * 2) / 16; i += 256) dst[i] = src[i];
    }
    {
        for (int i = t; i < 1024; i += 256) {
            int row = i >> 5, kq = i & 31;
            uint4 v = make_uint4(0, 0, 0, 0);
            if (n0 + row < N) v = ((const uint4*)(h2b + (size_t)(n0 + row) * 256))[kq];
            *(uint4*)(sA + row * KP2 + kq * 8) = v;
        }
    }
    __syncthreads();

    short8 af[8];
#pragma unroll
    for (int kc = 0; kc < 8; ++kc)
        af[kc] = *(const short8*)(sA + (rs * 16 + l15) * KP2 + kc * 32 + q * 8);

    f32x4 acc[2];
#pragma unroll
    for (int nt = 0; nt < 2; ++nt) {
        f32x4 a = {0.f, 0.f, 0.f, 0.f};
#pragma unroll
        for (int kc = 0; kc < 8; ++kc) {
            short8 bf = *(const short8*)(sB + (ch * 32 + nt * 16 + l15) * KP2 + kc * 32 + q * 8);
            a = __builtin_amdgcn_mfma_f32_16x16x32_bf16(af[kc], bf, a, 0, 0, 0);
        }
        acc[nt] = a;
    }

    float asv[2], adv[2];
#pragma unroll
    for (int nt = 0; nt < 2; ++nt) {
        int col = ch * 32 + nt * 16 + l15;
        asv[nt] = as2[col]; adv[nt] = ad2[col];
    }
#pragma unroll
    for (int r = 0; r < 4; ++r) {
        int row = n0 + rs * 16 + q * 4 + r;
        if (row < N) {
#pragma unroll
            for (int nt = 0; nt < 2; ++nt)
                h3b[(size_t)row * 64 + ch * 32 + nt * 16 + l15] = __float2bfloat16(acc[nt][r]);
        }
        float s = acc[0][r] * asv[0] + acc[1][r] * asv[1];
        float d = acc[0][r] * adv[0] + acc[1][r] * adv[1];
#pragma unroll
        for (int o = 1; o < 16; o <<= 1) { s += __shfl_xor(s, o); d += __shfl_xor(d, o); }
        if (l15 == 0 && row < N) {
            atomicAdd(&a_s2[row], s);
            atomicAdd(&a_d2[row], d);
        }
    }
}

// ============ Layer 2 fused softmax+aggregate + b2 -> out ============
// 8 dsts/block (4 waves x two 32-lane halves), no barriers, 16-deep ILP.
__global__ __launch_bounds__(256) void k_agg2_fused(const int* __restrict__ rowptr,
    const int* __restrict__ csr_src, const float* __restrict__ a_s2,
    const float* __restrict__ a_d2, const __hip_bfloat16* __restrict__ h3b,
    const float* __restrict__ b2, float* __restrict__ out, int N)
{
    const int tt = threadIdx.x, wv = tt >> 6, t = tt & 63;
    const int half = t >> 5, l = t & 31;
    const int dst = blockIdx.x * 8 + wv * 2 + half;
    const bool valid = dst < N;
    __shared__ int   s_off[4][2][32];
    __shared__ float s_ex[4][2][32];
    int start = 0, end = 0;
    float adv = 0.f;
    if (valid) { start = rowptr[dst]; end = rowptr[dst + 1]; adv = a_d2[dst]; }
    int trips = (end - start + 31) >> 5;
#pragma unroll
    for (int o = 32; o > 0; o >>= 1) { int u = __shfl_xor(trips, o); trips = u > trips ? u : trips; }
    const char* hbase = (const char*)h3b;
    float den = 0.f, acc0 = 0.f, acc1 = 0.f;

    for (int it = 0; it < trips; ++it) {
        int base = start + it * 32;
        int nloc = end - base; if (nloc > 32) nloc = 32; if (nloc < 0) nloc = 0;
        if (l < nloc) {
            int src = csr_src[base + l];
            s_off[wv][half][l] = src << 7;               // byte offset src*128
            float e = a_s2[src] + adv;
            e = e > 0.f ? e : NEG_SLOPE * e;
            float ex = __expf(e);
            s_ex[wv][half][l] = ex;
            den += ex;
        }
        int j = 0;
        for (; j + 15 < nloc; j += 16) {
            unsigned v[16];
#pragma unroll
            for (int q = 0; q < 16; ++q)
                v[q] = *(const unsigned*)(hbase + (size_t)(unsigned)s_off[wv][half][j + q] + l * 4);
#pragma unroll
            for (int q = 0; q < 16; ++q) {
                float e = s_ex[wv][half][j + q];
                acc0 += e * bflo(v[q]); acc1 += e * bfhi(v[q]);
            }
        }
        for (; j + 7 < nloc; j += 8) {
            unsigned v[8];
#pragma unroll
            for (int q = 0; q < 8; ++q)
                v[q] = *(const unsigned*)(hbase + (size_t)(unsigned)s_off[wv][half][j + q] + l * 4);
#pragma unroll
            for (int q = 0; q < 8; ++q) {
                float e = s_ex[wv][half][j + q];
                acc0 += e * bflo(v[q]); acc1 += e * bfhi(v[q]);
            }
        }
        for (; j < nloc; ++j) {
            unsigned v = *(const unsigned*)(hbase + (size_t)(unsigned)s_off[wv][half][j] + l * 4);
            float e = s_ex[wv][half][j];
            acc0 += e * bflo(v); acc1 += e * bfhi(v);
        }
    }
#pragma unroll
    for (int o = 16; o > 0; o >>= 1) den += __shfl_xor(den, o);
    if (valid) {
        float inv = 1.0f / den;
        float2 bb = ((const float2*)b2)[l];
        float2 ov; ov.x = acc0 * inv + bb.x; ov.y = acc1 * inv + bb.y;
        ((float2*)(out + (size_t)dst * 64))[l] = ov;
    }
}

extern "C" void kernel_launch(void* const* d_in, const int* in_sizes, int n_in,
                              void* d_out, int out_size, void* d_ws, size_t ws_size,
                              hipStream_t stream)
{
    const float* x   = (const float*)d_in[0];
    const int*   ei  = (const int*)d_in[1];
    const float* W1  = (const float*)d_in[2];
    const float* as1 = (const float*)d_in[3];
    const float* ad1 = (const float*)d_in[4];
    const float* b1  = (const float*)d_in[5];
    const float* W2  = (const float*)d_in[6];
    const float* as2 = (const float*)d_in[7];
    const float* ad2 = (const float*)d_in[8];
    const float* b2  = (const float*)d_in[9];
    float* out = (float*)d_out;

    const int N = in_sizes[0] / 128;      // 50000
    const int E = in_sizes[1] / 2;        // 800000
    const int M = E + N;                  // edges + self loops
    const int NB = (N + 255) / 256;       // scan blocks (196 <= 256)
    const int Eb = (E + 255) / 256;

    // ---- workspace layout (256B-aligned) ----
    char* w = (char*)d_ws;
    size_t o = 0;
    auto alloc = [&](size_t bytes) { size_t r = o; o = (o + bytes + 255) & ~(size_t)255; return r; };
    __hip_bfloat16* h1h   = (__hip_bfloat16*)(w + alloc((size_t)N * 256 * 2)); // 25.6 MB (4 head tables)
    float* a_s1h          = (float*)(w + alloc((size_t)N * 4 * 4));
    float* a_d1h          = (float*)(w + alloc((size_t)N * 4 * 4));
    __hip_bfloat16* h2b   = (__hip_bfloat16*)(w + alloc((size_t)N * 256 * 2)); // 25.6 MB
    __hip_bfloat16* h3b   = (__hip_bfloat16*)(w + alloc((size_t)N * 64 * 2));  // 6.4 MB
    // zero-block: a_s2 | a_d2 | deg — one memset covers the span
    size_t z0 = o;
    float* a_s2           = (float*)(w + alloc((size_t)N * 4));
    float* a_d2           = (float*)(w + alloc((size_t)N * 4));
    int* deg              = (int*)(w + alloc((size_t)N * 4));
    size_t z1 = o;
    int* rank             = (int*)(w + alloc((size_t)E * 4));                  // 3.2 MB
    int* rowptr           = (int*)(w + alloc((size_t)(N + 1) * 4));
    int* excl             = (int*)(w + alloc((size_t)N * 4));
    int* bsum             = (int*)(w + alloc((size_t)NB * 4));
    int* csr_src          = (int*)(w + alloc((size_t)M * 4));                  // 3.4 MB
    __hip_bfloat16* W1t   = (__hip_bfloat16*)(w + alloc((size_t)256 * KP * 2));
    __hip_bfloat16* W2t   = (__hip_bfloat16*)(w + alloc((size_t)64 * KP2 * 2));

    // ---- zero + init (edge hist/rank + weight prep fused) ----
    hipMemsetAsync(w + z0, 0, z1 - z0, stream);
    const int Pb = (256 * KP + 64 * KP2 + 255) / 256;
    k_init<<<Eb + Pb, 256, 0, stream>>>(ei, E, deg, rank, W1, W2, W1t, W2t, Eb);

    // ---- scan1 (tiny), then gemm1 (+ piggybacked scan23) ----
    k_scan1<<<NB, 256, 0, stream>>>(deg, N, excl, bsum);
    const int G1x = (N + 63) / 64;
    k_gemm1_mfma<<<dim3(G1x + (NB + 1) / 2, 2), 256, 0, stream>>>(
        x, W1t, as1, ad1, h1h, a_s1h, a_d1h, N, M, excl, bsum, rowptr, NB, G1x);

    // ---- scatter (atomic-free) ----
    k_scatter<<<(M + 255) / 256, 256, 0, stream>>>(ei, rank, E, N, rowptr, csr_src);

    // ---- layer 1 aggregate: head-split + 8-lane group per dst (deep ILP) ----
    const int DG1 = (N + 31) / 32;
    k_agg1g<<<4 * DG1, 256, 0, stream>>>(rowptr, csr_src, a_s1h, a_d1h, h1h, b1, h2b, N);

    // ---- layer 2 ----
    k_gemm2_mfma<<<(N + 31) / 32, 256, 0, stream>>>(h2b, W2t, as2, ad2, h3b, a_s2, a_d2, N);
    k_agg2_fused<<<(N + 7) / 8, 256, 0, stream>>>(rowptr, csr_src, a_s2, a_d2, h3b, b2, out, N);
}

// Round 8
// 247.922 us; speedup vs baseline: 1.2755x; 1.0385x over previous
//
#include <hip/hip_runtime.h>
#include <hip/hip_bf16.h>

#define NEG_SLOPE 0.2f

typedef __attribute__((ext_vector_type(8))) short short8;   // 8 bf16 (4 VGPRs)
typedef __attribute__((ext_vector_type(4))) float f32x4;    // MFMA accumulator

__device__ __forceinline__ float bflo(unsigned u) { return __uint_as_float(u << 16); }
__device__ __forceinline__ float bfhi(unsigned u) { return __uint_as_float(u & 0xffff0000u); }
__device__ __forceinline__ unsigned pk2bf(float a, float b) {
    __hip_bfloat162 t; t.x = __float2bfloat16(a); t.y = __float2bfloat16(b);
    return *reinterpret_cast<unsigned*>(&t);
}

#define KP  136   // padded k-stride for gemm1 tiles (128+8)
#define KP2 264   // padded k-stride for gemm2 tiles (256+8)

// ============ init: edge hist + rank (blocks [0,Eb)) + weight prep (rest) ============
__global__ void k_init(const int* __restrict__ ei, int E, int* __restrict__ deg,
    int* __restrict__ rank, const float* __restrict__ W1, const float* __restrict__ W2,
    __hip_bfloat16* __restrict__ W1t, __hip_bfloat16* __restrict__ W2t, int Eb)
{
    int b = blockIdx.x;
    if (b < Eb) {
        int i = b * 256 + threadIdx.x;
        if (i < E) {
            int dst = ei[E + i];
            rank[i] = atomicAdd(&deg[dst], 1);
        }
    } else {
        int i = (b - Eb) * 256 + threadIdx.x;
        if (i < 256 * KP) {
            int n = i / KP, k = i % KP;
            W1t[i] = __float2bfloat16(k < 128 ? W1[k * 256 + n] : 0.f);
        } else {
            int j = i - 256 * KP;
            if (j < 64 * KP2) {
                int n = j / KP2, k = j % KP2;
                W2t[j] = __float2bfloat16(k < 256 ? W2[k * 64 + n] : 0.f);
            }
        }
    }
}

// ============ scan1: per-256-block inclusive scan of (deg+1) -> excl + bsum ============
__global__ __launch_bounds__(256) void k_scan1(const int* __restrict__ deg, int N,
    int* __restrict__ excl, int* __restrict__ bsum)
{
    __shared__ int s[256];
    int t = threadIdx.x, i = blockIdx.x * 256 + t;
    int v = (i < N) ? deg[i] + 1 : 0;
    s[t] = v; __syncthreads();
#pragma unroll
    for (int o = 1; o < 256; o <<= 1) {
        int x = (t >= o) ? s[t - o] : 0;
        __syncthreads();
        s[t] += x;
        __syncthreads();
    }
    if (i < N) excl[i] = s[t] - v;
    if (t == 255) bsum[blockIdx.x] = s[255];
}

// ============ scatter: atomic-free (rank precomputed); self-loop at slot 0 ============
__global__ void k_scatter(const int* __restrict__ ei, const int* __restrict__ rank,
    int E, int N, const int* __restrict__ rowptr, int* __restrict__ csr_src)
{
    int i = blockIdx.x * blockDim.x + threadIdx.x;
    if (i < E) {
        int src = ei[i], dst = ei[E + i];
        csr_src[rowptr[dst] + 1 + rank[i]] = src;
    } else if (i < E + N) {
        int n = i - E;
        csr_src[rowptr[n]] = n;
    }
}

// ============ Layer 1 GEMM via MFMA + fused att dots + piggybacked scan23 ============
// h1 output is HEAD-MAJOR: h1h[h][N][64] (four contiguous 6.4MB tables) so the
// aggregate kernel can keep one head's table per XCD-L2. Att dots head-major too.
__global__ __launch_bounds__(256) void k_gemm1_mfma(
    const float* __restrict__ x, const __hip_bfloat16* __restrict__ W1t,
    const float* __restrict__ as1, const float* __restrict__ ad1,
    __hip_bfloat16* __restrict__ h1h, float* __restrict__ a_s1h, float* __restrict__ a_d1h,
    int N, int M, const int* __restrict__ excl, const int* __restrict__ bsum,
    int* __restrict__ rowptr, int NB, int G1x)
{
    __shared__ short sA[64 * KP];
    __shared__ short sB[128 * KP];

    if (blockIdx.x >= G1x) {
        int sb = (blockIdx.x - G1x) * 2 + blockIdx.y;
        if (sb >= NB) return;
        int* s = (int*)sA;
        int t = threadIdx.x;
        s[t] = (t < NB) ? bsum[t] : 0;
        __syncthreads();
#pragma unroll
        for (int o = 1; o < 256; o <<= 1) {
            int y = (t >= o) ? s[t - o] : 0;
            __syncthreads();
            s[t] += y;
            __syncthreads();
        }
        int off = (sb == 0) ? 0 : s[sb - 1];
        int i = sb * 256 + t;
        if (i < N) rowptr[i] = excl[i] + off;
        if (i == 0) rowptr[N] = M;
        return;
    }

    const int n0 = blockIdx.x * 64;
    const int c0 = blockIdx.y * 128;
    const int t = threadIdx.x, wv = t >> 6, lane = t & 63;
    const int l15 = lane & 15, q = lane >> 4;

    {
        const float4* x4 = (const float4*)x;
        for (int i = t; i < 2048; i += 256) {
            int row = i >> 5, kq = i & 31;
            float4 v = make_float4(0.f, 0.f, 0.f, 0.f);
            if (n0 + row < N) v = x4[(size_t)(n0 + row) * 32 + kq];
            uint2 p; p.x = pk2bf(v.x, v.y); p.y = pk2bf(v.z, v.w);
            *(uint2*)(sA + row * KP + kq * 4) = p;
        }
    }
    {
        const uint4* src = (const uint4*)((const short*)W1t + (size_t)c0 * KP);
        uint4* dst = (uint4*)sB;
        for (int i = t; i < (128 * KP * 2) / 16; i += 256) dst[i] = src[i];
    }
    __syncthreads();

    short8 af[4];
#pragma unroll
    for (int kc = 0; kc < 4; ++kc)
        af[kc] = *(const short8*)(sA + (wv * 16 + l15) * KP + kc * 32 + q * 8);

    f32x4 acc[8];
#pragma unroll
    for (int nt = 0; nt < 8; ++nt) {
        f32x4 a = {0.f, 0.f, 0.f, 0.f};
#pragma unroll
        for (int kc = 0; kc < 4; ++kc) {
            short8 bf = *(const short8*)(sB + (nt * 16 + l15) * KP + kc * 32 + q * 8);
            a = __builtin_amdgcn_mfma_f32_16x16x32_bf16(af[kc], bf, a, 0, 0, 0);
        }
        acc[nt] = a;
    }

    // head-major store: col = c0 + nt*16 + l15 -> table col>>6, inner col&63
#pragma unroll
    for (int nt = 0; nt < 8; ++nt) {
        int col = c0 + nt * 16 + l15;
        __hip_bfloat16* tp = h1h + ((size_t)(col >> 6) * N) * 64 + (col & 63);
#pragma unroll
        for (int r = 0; r < 4; ++r) {
            int row = n0 + wv * 16 + q * 4 + r;
            if (row < N)
                tp[(size_t)row * 64] = __float2bfloat16(acc[nt][r]);
        }
    }

    float asv[8], adv[8];
#pragma unroll
    for (int nt = 0; nt < 8; ++nt) {
        asv[nt] = as1[c0 + nt * 16 + l15];
        adv[nt] = ad1[c0 + nt * 16 + l15];
    }
    const int hb = blockIdx.y * 2;
#pragma unroll
    for (int r = 0; r < 4; ++r) {
        float slo = 0.f, shi = 0.f, dlo = 0.f, dhi = 0.f;
#pragma unroll
        for (int nt = 0; nt < 4; ++nt) { slo += acc[nt][r] * asv[nt]; dlo += acc[nt][r] * adv[nt]; }
#pragma unroll
        for (int nt = 4; nt < 8; ++nt) { shi += acc[nt][r] * asv[nt]; dhi += acc[nt][r] * adv[nt]; }
#pragma unroll
        for (int o = 1; o < 16; o <<= 1) {
            slo += __shfl_xor(slo, o); shi += __shfl_xor(shi, o);
            dlo += __shfl_xor(dlo, o); dhi += __shfl_xor(dhi, o);
        }
        int row = n0 + wv * 16 + q * 4 + r;
        if (l15 == 0 && row < N) {
            a_s1h[(size_t)hb * N + row]       = slo;
            a_s1h[(size_t)(hb + 1) * N + row] = shi;
            a_d1h[(size_t)hb * N + row]       = dlo;
            a_d1h[(size_t)(hb + 1) * N + row] = dhi;
        }
    }
}

// ============ Layer 1 head-split aggregate, 8-lane group per dst + prefetch ============
// head = blockIdx.x % 4 (XCD-local 6.4MB table, -44% FETCH proven in r6/r7).
// Wave = 8 groups of 8 lanes; lane c owns cols [8c,8c+8) -> no accumulator reduce.
// NEW (r8): double-buffered metadata prefetch — batch i+1's (csr, a_s, exp) is
// computed while batch i's 8 gathers are in flight, breaking the serial
// csr->a_s->exp->gather chain that left gathers idle.
__global__ __launch_bounds__(256) void k_agg1g(const int* __restrict__ rowptr,
    const int* __restrict__ csr_src, const float* __restrict__ a_s1h,
    const float* __restrict__ a_d1h, const __hip_bfloat16* __restrict__ h1h,
    const float* __restrict__ b1, __hip_bfloat16* __restrict__ h2b, int N)
{
    const int tt = threadIdx.x, wv = tt >> 6, l = tt & 63;
    const int h = blockIdx.x & 3;
    const int dgrp = blockIdx.x >> 2;
    const int g = l >> 3, c = l & 7;
    const char* tab = (const char*)(h1h + (size_t)h * N * 64);
    const float* ash = a_s1h + (size_t)h * N;
    __shared__ int   s_off[4][2][8][8];
    __shared__ float s_ex[4][2][8][8];

    const int dst = dgrp * 32 + wv * 8 + g;
    const bool valid = dst < N;
    int st = 0, en = 0;
    if (valid) { st = rowptr[dst]; en = rowptr[dst + 1]; }
    float adh = valid ? a_d1h[(size_t)h * N + dst] : 0.f;
    float a0 = 0.f, a1 = 0.f, a2 = 0.f, a3 = 0.f;
    float a4 = 0.f, a5 = 0.f, a6 = 0.f, a7 = 0.f;
    float dn = 0.f;

    // prologue: batch 0 metadata into parity 0
    {
        int m = st + c;
        bool k = m < en;
        int src = csr_src[k ? m : 0];
        float e = ash[src] + adh;
        e = e > 0.f ? e : NEG_SLOPE * e;
        float ex = k ? __expf(e) : 0.f;
        s_off[wv][0][g][c] = src << 7;            // byte offset src*128
        s_ex[wv][0][g][c] = ex;
        dn += ex;
    }
    int pb = 0;
    for (int base = st; base < en; base += 8) {
        uint4 v[8];
#pragma unroll
        for (int j = 0; j < 8; ++j)
            v[j] = *(const uint4*)(tab + (size_t)(unsigned)s_off[wv][pb][g][j] + c * 16);
        int nb = base + 8;
        if (nb < en) {                            // prefetch next batch metadata
            int m = nb + c;
            bool k = m < en;
            int src = csr_src[k ? m : 0];
            float e = ash[src] + adh;
            e = e > 0.f ? e : NEG_SLOPE * e;
            float ex = k ? __expf(e) : 0.f;
            s_off[wv][pb ^ 1][g][c] = src << 7;
            s_ex[wv][pb ^ 1][g][c] = ex;
            dn += ex;
        }
#pragma unroll
        for (int j = 0; j < 8; ++j) {
            float exj = s_ex[wv][pb][g][j];
            a0 += exj * bflo(v[j].x); a1 += exj * bfhi(v[j].x);
            a2 += exj * bflo(v[j].y); a3 += exj * bfhi(v[j].y);
            a4 += exj * bflo(v[j].z); a5 += exj * bfhi(v[j].z);
            a6 += exj * bflo(v[j].w); a7 += exj * bfhi(v[j].w);
        }
        pb ^= 1;
    }
    // denominator reduce within the 8-lane group
    dn += __shfl_xor(dn, 1); dn += __shfl_xor(dn, 2); dn += __shfl_xor(dn, 4);
    if (!valid) return;
    float inv = 1.0f / dn;
    float4 bb0 = ((const float4*)b1)[h * 16 + c * 2];
    float4 bb1 = ((const float4*)b1)[h * 16 + c * 2 + 1];
    float v0 = a0 * inv + bb0.x; v0 = v0 > 0.f ? v0 : (__expf(v0) - 1.f);
    float v1 = a1 * inv + bb0.y; v1 = v1 > 0.f ? v1 : (__expf(v1) - 1.f);
    float v2 = a2 * inv + bb0.z; v2 = v2 > 0.f ? v2 : (__expf(v2) - 1.f);
    float v3 = a3 * inv + bb0.w; v3 = v3 > 0.f ? v3 : (__expf(v3) - 1.f);
    float v4 = a4 * inv + bb1.x; v4 = v4 > 0.f ? v4 : (__expf(v4) - 1.f);
    float v5 = a5 * inv + bb1.y; v5 = v5 > 0.f ? v5 : (__expf(v5) - 1.f);
    float v6 = a6 * inv + bb1.z; v6 = v6 > 0.f ? v6 : (__expf(v6) - 1.f);
    float v7 = a7 * inv + bb1.w; v7 = v7 > 0.f ? v7 : (__expf(v7) - 1.f);
    uint4 pkt;
    pkt.x = pk2bf(v0, v1); pkt.y = pk2bf(v2, v3);
    pkt.z = pk2bf(v4, v5); pkt.w = pk2bf(v6, v7);
    *(uint4*)((char*)h2b + (size_t)dst * 512 + h * 128 + c * 16) = pkt;
}

// ============ Layer 2 GEMM via MFMA + fused att dots (direct stores) ============
__global__ __launch_bounds__(256) void k_gemm2_mfma(
    const __hip_bfloat16* __restrict__ h2b, const __hip_bfloat16* __restrict__ W2t,
    const float* __restrict__ as2, const float* __restrict__ ad2,
    __hip_bfloat16* __restrict__ h3b, float* __restrict__ a_s2, float* __restrict__ a_d2,
    int N)
{
    const int n0 = blockIdx.x * 32;
    const int t = threadIdx.x, wv = t >> 6, lane = t & 63;
    const int l15 = lane & 15, q = lane >> 4;
    const int rs = wv & 1, ch = wv >> 1;

    __shared__ short sA[32 * KP2];
    __shared__ short sB[64 * KP2];

    {
        const uint4* src = (const uint4*)W2t;
        uint4* dst = (uint4*)sB;
        for (int i = t; i < (64 * KP2 * 2) / 16; i += 256) dst[i] = src[i];
    }
    {
        for (int i = t; i < 1024; i += 256) {
            int row = i >> 5, kq = i & 31;
            uint4 v = make_uint4(0, 0, 0, 0);
            if (n0 + row < N) v = ((const uint4*)(h2b + (size_t)(n0 + row) * 256))[kq];
            *(uint4*)(sA + row * KP2 + kq * 8) = v;
        }
    }
    __syncthreads();

    short8 af[8];
#pragma unroll
    for (int kc = 0; kc < 8; ++kc)
        af[kc] = *(const short8*)(sA + (rs * 16 + l15) * KP2 + kc * 32 + q * 8);

    f32x4 acc[2];
#pragma unroll
    for (int nt = 0; nt < 2; ++nt) {
        f32x4 a = {0.f, 0.f, 0.f, 0.f};
#pragma unroll
        for (int kc = 0; kc < 8; ++kc) {
            short8 bf = *(const short8*)(sB + (ch * 32 + nt * 16 + l15) * KP2 + kc * 32 + q * 8);
            a = __builtin_amdgcn_mfma_f32_16x16x32_bf16(af[kc], bf, a, 0, 0, 0);
        }
        acc[nt] = a;
    }

    float asv[2], adv[2];
#pragma unroll
    for (int nt = 0; nt < 2; ++nt) {
        int col = ch * 32 + nt * 16 + l15;
        asv[nt] = as2[col]; adv[nt] = ad2[col];
    }
#pragma unroll
    for (int r = 0; r < 4; ++r) {
        int row = n0 + rs * 16 + q * 4 + r;
        if (row < N) {
#pragma unroll
            for (int nt = 0; nt < 2; ++nt)
                h3b[(size_t)row * 64 + ch * 32 + nt * 16 + l15] = __float2bfloat16(acc[nt][r]);
        }
        float s = acc[0][r] * asv[0] + acc[1][r] * asv[1];
        float d = acc[0][r] * adv[0] + acc[1][r] * adv[1];
#pragma unroll
        for (int o = 1; o < 16; o <<= 1) { s += __shfl_xor(s, o); d += __shfl_xor(d, o); }
        if (l15 == 0 && row < N) {
            atomicAdd(&a_s2[row], s);
            atomicAdd(&a_d2[row], d);
        }
    }
}

// ============ Layer 2 aggregate, 8-lane group per dst + prefetch (r7 structure) ============
// Same skeleton as k_agg1g: 32 dsts/block, lane c owns cols [8c,8c+8) of the 128B
// h3b row (one uint4), 8 gathers in flight, metadata double-buffer prefetch,
// no accumulator shuffles (vs old: 256B/load-inst + trips-voted masked loop).
__global__ __launch_bounds__(256) void k_agg2g(const int* __restrict__ rowptr,
    const int* __restrict__ csr_src, const float* __restrict__ a_s2,
    const float* __restrict__ a_d2, const __hip_bfloat16* __restrict__ h3b,
    const float* __restrict__ b2, float* __restrict__ out, int N)
{
    const int tt = threadIdx.x, wv = tt >> 6, l = tt & 63;
    const int g = l >> 3, c = l & 7;
    const char* tab = (const char*)h3b;
    __shared__ int   s_off[4][2][8][8];
    __shared__ float s_ex[4][2][8][8];

    const int dst = blockIdx.x * 32 + wv * 8 + g;
    const bool valid = dst < N;
    int st = 0, en = 0;
    if (valid) { st = rowptr[dst]; en = rowptr[dst + 1]; }
    float adv = valid ? a_d2[dst] : 0.f;
    float a0 = 0.f, a1 = 0.f, a2 = 0.f, a3 = 0.f;
    float a4 = 0.f, a5 = 0.f, a6 = 0.f, a7 = 0.f;
    float dn = 0.f;

    {
        int m = st + c;
        bool k = m < en;
        int src = csr_src[k ? m : 0];
        float e = a_s2[src] + adv;
        e = e > 0.f ? e : NEG_SLOPE * e;
        float ex = k ? __expf(e) : 0.f;
        s_off[wv][0][g][c] = src << 7;            // byte offset src*128
        s_ex[wv][0][g][c] = ex;
        dn += ex;
    }
    int pb = 0;
    for (int base = st; base < en; base += 8) {
        uint4 v[8];
#pragma unroll
        for (int j = 0; j < 8; ++j)
            v[j] = *(const uint4*)(tab + (size_t)(unsigned)s_off[wv][pb][g][j] + c * 16);
        int nb = base + 8;
        if (nb < en) {
            int m = nb + c;
            bool k = m < en;
            int src = csr_src[k ? m : 0];
            float e = a_s2[src] + adv;
            e = e > 0.f ? e : NEG_SLOPE * e;
            float ex = k ? __expf(e) : 0.f;
            s_off[wv][pb ^ 1][g][c] = src << 7;
            s_ex[wv][pb ^ 1][g][c] = ex;
            dn += ex;
        }
#pragma unroll
        for (int j = 0; j < 8; ++j) {
            float exj = s_ex[wv][pb][g][j];
            a0 += exj * bflo(v[j].x); a1 += exj * bfhi(v[j].x);
            a2 += exj * bflo(v[j].y); a3 += exj * bfhi(v[j].y);
            a4 += exj * bflo(v[j].z); a5 += exj * bfhi(v[j].z);
            a6 += exj * bflo(v[j].w); a7 += exj * bfhi(v[j].w);
        }
        pb ^= 1;
    }
    dn += __shfl_xor(dn, 1); dn += __shfl_xor(dn, 2); dn += __shfl_xor(dn, 4);
    if (!valid) return;
    float inv = 1.0f / dn;
    float4 bb0 = ((const float4*)b2)[c * 2];
    float4 bb1 = ((const float4*)b2)[c * 2 + 1];
    float4 o0, o1;
    o0.x = a0 * inv + bb0.x; o0.y = a1 * inv + bb0.y;
    o0.z = a2 * inv + bb0.z; o0.w = a3 * inv + bb0.w;
    o1.x = a4 * inv + bb1.x; o1.y = a5 * inv + bb1.y;
    o1.z = a6 * inv + bb1.z; o1.w = a7 * inv + bb1.w;
    float4* op = (float4*)(out + (size_t)dst * 64);
    op[c * 2] = o0; op[c * 2 + 1] = o1;
}

extern "C" void kernel_launch(void* const* d_in, const int* in_sizes, int n_in,
                              void* d_out, int out_size, void* d_ws, size_t ws_size,
                              hipStream_t stream)
{
    const float* x   = (const float*)d_in[0];
    const int*   ei  = (const int*)d_in[1];
    const float* W1  = (const float*)d_in[2];
    const float* as1 = (const float*)d_in[3];
    const float* ad1 = (const float*)d_in[4];
    const float* b1  = (const float*)d_in[5];
    const float* W2  = (const float*)d_in[6];
    const float* as2 = (const float*)d_in[7];
    const float* ad2 = (const float*)d_in[8];
    const float* b2  = (const float*)d_in[9];
    float* out = (float*)d_out;

    const int N = in_sizes[0] / 128;      // 50000
    const int E = in_sizes[1] / 2;        // 800000
    const int M = E + N;                  // edges + self loops
    const int NB = (N + 255) / 256;       // scan blocks (196 <= 256)
    const int Eb = (E + 255) / 256;

    // ---- workspace layout (256B-aligned) ----
    char* w = (char*)d_ws;
    size_t o = 0;
    auto alloc = [&](size_t bytes) { size_t r = o; o = (o + bytes + 255) & ~(size_t)255; return r; };
    __hip_bfloat16* h1h   = (__hip_bfloat16*)(w + alloc((size_t)N * 256 * 2)); // 25.6 MB (4 head tables)
    float* a_s1h          = (float*)(w + alloc((size_t)N * 4 * 4));
    float* a_d1h          = (float*)(w + alloc((size_t)N * 4 * 4));
    __hip_bfloat16* h2b   = (__hip_bfloat16*)(w + alloc((size_t)N * 256 * 2)); // 25.6 MB
    __hip_bfloat16* h3b   = (__hip_bfloat16*)(w + alloc((size_t)N * 64 * 2));  // 6.4 MB
    // zero-block: a_s2 | a_d2 | deg — one memset covers the span
    size_t z0 = o;
    float* a_s2           = (float*)(w + alloc((size_t)N * 4));
    float* a_d2           = (float*)(w + alloc((size_t)N * 4));
    int* deg              = (int*)(w + alloc((size_t)N * 4));
    size_t z1 = o;
    int* rank             = (int*)(w + alloc((size_t)E * 4));                  // 3.2 MB
    int* rowptr           = (int*)(w + alloc((size_t)(N + 1) * 4));
    int* excl             = (int*)(w + alloc((size_t)N * 4));
    int* bsum             = (int*)(w + alloc((size_t)NB * 4));
    int* csr_src          = (int*)(w + alloc((size_t)M * 4));                  // 3.4 MB
    __hip_bfloat16* W1t   = (__hip_bfloat16*)(w + alloc((size_t)256 * KP * 2));
    __hip_bfloat16* W2t   = (__hip_bfloat16*)(w + alloc((size_t)64 * KP2 * 2));

    // ---- zero + init (edge hist/rank + weight prep fused) ----
    hipMemsetAsync(w + z0, 0, z1 - z0, stream);
    const int Pb = (256 * KP + 64 * KP2 + 255) / 256;
    k_init<<<Eb + Pb, 256, 0, stream>>>(ei, E, deg, rank, W1, W2, W1t, W2t, Eb);

    // ---- scan1 (tiny), then gemm1 (+ piggybacked scan23) ----
    k_scan1<<<NB, 256, 0, stream>>>(deg, N, excl, bsum);
    const int G1x = (N + 63) / 64;
    k_gemm1_mfma<<<dim3(G1x + (NB + 1) / 2, 2), 256, 0, stream>>>(
        x, W1t, as1, ad1, h1h, a_s1h, a_d1h, N, M, excl, bsum, rowptr, NB, G1x);

    // ---- scatter (atomic-free) ----
    k_scatter<<<(M + 255) / 256, 256, 0, stream>>>(ei, rank, E, N, rowptr, csr_src);

    // ---- layer 1 aggregate: head-split + 8-lane groups + metadata prefetch ----
    const int DG1 = (N + 31) / 32;
    k_agg1g<<<4 * DG1, 256, 0, stream>>>(rowptr, csr_src, a_s1h, a_d1h, h1h, b1, h2b, N);

    // ---- layer 2 ----
    k_gemm2_mfma<<<(N + 31) / 32, 256, 0, stream>>>(h2b, W2t, as2, ad2, h3b, a_s2, a_d2, N);
    k_agg2g<<<DG1, 256, 0, stream>>>(rowptr, csr_src, a_s2, a_d2, h3b, b2, out, N);
}